// Round 1
// baseline (14584.610 us; speedup 1.0000x reference)
//
#include <hip/hip_runtime.h>
#include <hip/hip_bf16.h>
#include <math.h>

// Problem dims (fixed)
#define BB 2
#define LL 1024
#define DM 768
#define NL 8
#define DS 16
#define DC 4
#define DI 1536
#define DTR 48
#define NTOK (BB*LL)          // 2048
#define WXROWS (DTR + 2*DS)   // 80

// ---------------- transpose input: batch[b,d,l] -> h[b,l,d] ----------------
__global__ __launch_bounds__(256) void transpose_in_kernel(
    const float* __restrict__ batch, float* __restrict__ h)
{
    int idx = blockIdx.x * 256 + threadIdx.x;
    if (idx >= BB*LL*DM) return;
    int d = idx % DM;
    int l = (idx / DM) % LL;
    int b = idx / (DM * LL);
    h[idx] = batch[((size_t)b*DM + d)*LL + l];
}

// ---------------- lengths from mask (robust to bool vs int32) ----------------
__global__ void lengths_kernel(const void* __restrict__ mask, int* __restrict__ lengths)
{
    int b = threadIdx.x;
    if (b >= BB) return;
    const unsigned int* mi = (const unsigned int*)mask;
    bool packed = (mi[0] == 0x01010101u);   // lengths >= 512, so first 4 bools are true
    int cnt = 0;
    if (packed) {
        const unsigned char* mb = (const unsigned char*)mask;
        for (int i = 0; i < LL; ++i) cnt += (mb[(size_t)b*LL + i] != 0);
    } else {
        for (int i = 0; i < LL; ++i) cnt += (mi[(size_t)b*LL + i] != 0);
    }
    lengths[b] = cnt;
}

// ---------------- RMSNorm (per token, D=768) ----------------
__global__ __launch_bounds__(256) void rmsnorm_kernel(
    const float* __restrict__ x, const float* __restrict__ w, float* __restrict__ o)
{
    int tok = blockIdx.x;
    const float* xr = x + (size_t)tok * DM;
    float ss = 0.f;
    for (int j = threadIdx.x; j < DM; j += 256) { float v = xr[j]; ss += v*v; }
    #pragma unroll
    for (int off = 32; off > 0; off >>= 1) ss += __shfl_down(ss, off);
    __shared__ float red[4];
    int lane = threadIdx.x & 63, wv = threadIdx.x >> 6;
    if (lane == 0) red[wv] = ss;
    __syncthreads();
    if (threadIdx.x == 0) {
        float t = red[0] + red[1] + red[2] + red[3];
        red[0] = rsqrtf(t / (float)DM + 1e-5f);
    }
    __syncthreads();
    float r = red[0];
    for (int j = threadIdx.x; j < DM; j += 256)
        o[(size_t)tok*DM + j] = xr[j] * w[j] * r;
}

// ---------------- generic tiled f32 GEMM: C[m,n] (+)= act( sum_k A[m,k]*W[n,k] + bias[n] ) ----------------
// A: lda row stride. W: [N,K] row-major. act: 0 none, 1 softplus. accum: 0 store, 1 add.
__global__ __launch_bounds__(256) void gemm_bt_kernel(
    const float* __restrict__ A, int lda,
    const float* __restrict__ W,
    const float* __restrict__ bias,
    float* __restrict__ C, int ldc,
    int M, int N, int K, int act, int accum)
{
    __shared__ float As[16][65];
    __shared__ float Ws[16][65];
    const int bm = blockIdx.y * 64;
    const int bn = blockIdx.x * 64;
    const int tid = threadIdx.x;
    const int tm = (tid >> 4) << 2;
    const int tn = (tid & 15) << 2;
    float acc[4][4] = {};
    for (int k0 = 0; k0 < K; k0 += 16) {
        #pragma unroll
        for (int i = 0; i < 4; ++i) {
            int idx = tid + i * 256;       // 0..1023
            int m  = idx >> 4;
            int kk = idx & 15;
            int gm = bm + m, gk = k0 + kk;
            As[kk][m] = (gm < M && gk < K) ? A[(size_t)gm*lda + gk] : 0.f;
            int gn = bn + m;
            Ws[kk][m] = (gn < N && gk < K) ? W[(size_t)gn*K + gk] : 0.f;
        }
        __syncthreads();
        #pragma unroll
        for (int kk = 0; kk < 16; ++kk) {
            float a[4], w[4];
            #pragma unroll
            for (int ii = 0; ii < 4; ++ii) a[ii] = As[kk][tm+ii];
            #pragma unroll
            for (int jj = 0; jj < 4; ++jj) w[jj] = Ws[kk][tn+jj];
            #pragma unroll
            for (int ii = 0; ii < 4; ++ii)
                #pragma unroll
                for (int jj = 0; jj < 4; ++jj)
                    acc[ii][jj] = fmaf(a[ii], w[jj], acc[ii][jj]);
        }
        __syncthreads();
    }
    #pragma unroll
    for (int ii = 0; ii < 4; ++ii) {
        int gm = bm + tm + ii;
        if (gm >= M) continue;
        #pragma unroll
        for (int jj = 0; jj < 4; ++jj) {
            int gn = bn + tn + jj;
            if (gn >= N) continue;
            float v = acc[ii][jj];
            if (bias) v += bias[gn];
            if (act == 1) v = (v > 20.f) ? v : log1pf(expf(v));
            size_t o = (size_t)gm*ldc + gn;
            if (accum) C[o] += v; else C[o] = v;
        }
    }
}

// ---------------- causal depthwise conv4 + bias + SiLU ----------------
// xc = xz[..., 0:DI]; u[b,l,d] = silu(sum_k xc[b,l-3+k,d]*cw[d,k] + cb[d])
__global__ __launch_bounds__(256) void conv_silu_kernel(
    const float* __restrict__ xz, const float* __restrict__ cw,
    const float* __restrict__ cb, float* __restrict__ u)
{
    int idx = blockIdx.x * 256 + threadIdx.x;
    if (idx >= BB*LL*DI) return;
    int d = idx % DI;
    int l = (idx / DI) % LL;
    int b = idx / (DI * LL);
    float acc = cb[d];
    #pragma unroll
    for (int k = 0; k < 4; ++k) {
        int ls = l - 3 + k;
        if (ls >= 0)
            acc = fmaf(xz[((size_t)(b*LL + ls))*(2*DI) + d], cw[d*4 + k], acc);
    }
    u[idx] = acc / (1.f + expf(-acc));
}

// ---------------- selective scan, one thread per (b, d) ----------------
// yfull[b,l,d] = ( scan_y + u*Dsk ) * silu(z) ; written in-place over delta (safe: same-element)
__global__ __launch_bounds__(256) void scan_kernel(
    const float* __restrict__ delta, const float* __restrict__ u,
    const float* __restrict__ dbl, const float* __restrict__ xz,
    const float* __restrict__ A_log, const float* __restrict__ Dsk,
    float* __restrict__ yfull)
{
    const int b = blockIdx.y;
    const int d = blockIdx.x * 256 + threadIdx.x;
    float A[DS], h[DS];
    #pragma unroll
    for (int s = 0; s < DS; ++s) { A[s] = -expf(A_log[(size_t)d*DS + s]); h[s] = 0.f; }
    const float dsk = Dsk[d];
    for (int t = 0; t < LL; ++t) {
        const size_t row = (size_t)b*LL + t;
        const float* bc = dbl + row*WXROWS + DTR;   // B then C, 16 each
        float Bs[DS], Cs[DS];
        #pragma unroll
        for (int s = 0; s < DS; ++s) { Bs[s] = bc[s]; Cs[s] = bc[DS+s]; }
        float dt = delta[row*DI + d];
        float ut = u[row*DI + d];
        float du = dt * ut;
        float y = 0.f;
        #pragma unroll
        for (int s = 0; s < DS; ++s) {
            h[s] = fmaf(expf(dt * A[s]), h[s], du * Bs[s]);
            y = fmaf(h[s], Cs[s], y);
        }
        float zt = xz[row*(2*DI) + DI + d];
        float sz = zt / (1.f + expf(-zt));
        yfull[row*DI + d] = (y + ut * dsk) * sz;
    }
}

// ---------------- final rmsnorm + gather last valid token ----------------
__global__ __launch_bounds__(256) void final_kernel(
    const float* __restrict__ h, const float* __restrict__ w,
    const int* __restrict__ lengths, float* __restrict__ out)
{
    int b = blockIdx.x;
    int idx = lengths[b] - 1;
    const float* xr = h + ((size_t)b*LL + idx)*DM;
    float ss = 0.f;
    for (int j = threadIdx.x; j < DM; j += 256) { float v = xr[j]; ss += v*v; }
    #pragma unroll
    for (int off = 32; off > 0; off >>= 1) ss += __shfl_down(ss, off);
    __shared__ float red[4];
    int lane = threadIdx.x & 63, wv = threadIdx.x >> 6;
    if (lane == 0) red[wv] = ss;
    __syncthreads();
    if (threadIdx.x == 0) {
        float t = red[0] + red[1] + red[2] + red[3];
        red[0] = rsqrtf(t / (float)DM + 1e-5f);
    }
    __syncthreads();
    float r = red[0];
    for (int j = threadIdx.x; j < DM; j += 256)
        out[(size_t)b*DM + j] = xr[j] * w[j] * r;
}

extern "C" void kernel_launch(void* const* d_in, const int* in_sizes, int n_in,
                              void* d_out, int out_size, void* d_ws, size_t ws_size,
                              hipStream_t stream)
{
    const float* batch   = (const float*)d_in[0];
    const void*  mask    = d_in[1];
    const float* norm_w  = (const float*)d_in[2];
    const float* W_in    = (const float*)d_in[3];
    const float* conv_w  = (const float*)d_in[4];
    const float* conv_b  = (const float*)d_in[5];
    const float* W_x     = (const float*)d_in[6];
    const float* W_dt    = (const float*)d_in[7];
    const float* b_dt    = (const float*)d_in[8];
    const float* A_log   = (const float*)d_in[9];
    const float* D_skip  = (const float*)d_in[10];
    const float* W_out   = (const float*)d_in[11];
    const float* normf_w = (const float*)d_in[12];
    float* out = (float*)d_out;

    // workspace layout (floats)
    float* ws    = (float*)d_ws;
    float* h     = ws;                     // 2*1024*768   = 1,572,864
    float* xn    = h    + (size_t)NTOK*DM; // 1,572,864
    float* xz    = xn   + (size_t)NTOK*DM; // 2*1024*3072  = 6,291,456
    float* u     = xz   + (size_t)NTOK*2*DI; // 3,145,728
    float* dbl   = u    + (size_t)NTOK*DI; // 2*1024*80    = 163,840
    float* delta = dbl  + (size_t)NTOK*WXROWS; // 3,145,728 (also yfull, in-place)
    int*   lengths = (int*)(delta + (size_t)NTOK*DI);

    // input transpose + lengths
    transpose_in_kernel<<<(BB*LL*DM + 255)/256, 256, 0, stream>>>(batch, h);
    lengths_kernel<<<1, 64, 0, stream>>>(mask, lengths);

    for (int i = 0; i < NL; ++i) {
        const float* Wi   = W_in  + (size_t)i * 2*DI * DM;
        const float* cwi  = conv_w + (size_t)i * DI * DC;
        const float* cbi  = conv_b + (size_t)i * DI;
        const float* Wxi  = W_x   + (size_t)i * WXROWS * DI;
        const float* Wdti = W_dt  + (size_t)i * DI * DTR;
        const float* bdti = b_dt  + (size_t)i * DI;
        const float* Ali  = A_log + (size_t)i * DI * DS;
        const float* Dski = D_skip + (size_t)i * DI;
        const float* Woi  = W_out + (size_t)i * DM * DI;

        // 1) pre-norm
        rmsnorm_kernel<<<NTOK, 256, 0, stream>>>(h, norm_w + (size_t)i*DM, xn);
        // 2) xz = xn @ W_in^T   [2048 x 3072]
        gemm_bt_kernel<<<dim3((2*DI+63)/64, (NTOK+63)/64), 256, 0, stream>>>(
            xn, DM, Wi, nullptr, xz, 2*DI, NTOK, 2*DI, DM, 0, 0);
        // 3) causal conv + SiLU -> u  [2048 x 1536]
        conv_silu_kernel<<<(BB*LL*DI + 255)/256, 256, 0, stream>>>(xz, cwi, cbi, u);
        // 4) dbl = u @ W_x^T  [2048 x 80]
        gemm_bt_kernel<<<dim3((WXROWS+63)/64, (NTOK+63)/64), 256, 0, stream>>>(
            u, DI, Wxi, nullptr, dbl, WXROWS, NTOK, WXROWS, DI, 0, 0);
        // 5) delta = softplus(dtp @ W_dt^T + b_dt)  [2048 x 1536]
        gemm_bt_kernel<<<dim3((DI+63)/64, (NTOK+63)/64), 256, 0, stream>>>(
            dbl, WXROWS, Wdti, bdti, delta, DI, NTOK, DI, DTR, 1, 0);
        // 6) selective scan -> yfull (in-place over delta)
        scan_kernel<<<dim3(DI/256, BB), 256, 0, stream>>>(
            delta, u, dbl, xz, Ali, Dski, delta);
        // 7) h += yfull @ W_out^T  [2048 x 768]
        gemm_bt_kernel<<<dim3((DM+63)/64, (NTOK+63)/64), 256, 0, stream>>>(
            delta, DI, Woi, nullptr, h, DM, NTOK, DM, DI, 0, 1);
    }

    final_kernel<<<BB, 256, 0, stream>>>(h, normf_w, lengths, out);
}

// Round 2
// 6101.189 us; speedup vs baseline: 2.3905x; 2.3905x over previous
//
#include <hip/hip_runtime.h>
#include <hip/hip_bf16.h>
#include <math.h>

// Problem dims (fixed)
#define BB 2
#define LL 1024
#define DM 768
#define NL 8
#define DS 16
#define DC 4
#define DI 1536
#define DTR 48
#define NTOK (BB*LL)          // 2048
#define WXROWS (DTR + 2*DS)   // 80
#define NC 32                 // scan chunks
#define CT (LL/NC)            // 32 timesteps per chunk

// ---------------- transpose input: batch[b,d,l] -> h[b,l,d] ----------------
__global__ __launch_bounds__(256) void transpose_in_kernel(
    const float* __restrict__ batch, float* __restrict__ h)
{
    int idx = blockIdx.x * 256 + threadIdx.x;
    if (idx >= BB*LL*DM) return;
    int d = idx % DM;
    int l = (idx / DM) % LL;
    int b = idx / (DM * LL);
    h[idx] = batch[((size_t)b*DM + d)*LL + l];
}

// ---------------- lengths from mask (robust to bool vs int32) ----------------
__global__ void lengths_kernel(const void* __restrict__ mask, int* __restrict__ lengths)
{
    int b = threadIdx.x;
    if (b >= BB) return;
    const unsigned int* mi = (const unsigned int*)mask;
    bool packed = (mi[0] == 0x01010101u);   // lengths >= 512, so first 4 bools are true
    int cnt = 0;
    if (packed) {
        const unsigned char* mb = (const unsigned char*)mask;
        for (int i = 0; i < LL; ++i) cnt += (mb[(size_t)b*LL + i] != 0);
    } else {
        for (int i = 0; i < LL; ++i) cnt += (mi[(size_t)b*LL + i] != 0);
    }
    lengths[b] = cnt;
}

// ---------------- RMSNorm (per token, D=768) ----------------
__global__ __launch_bounds__(256) void rmsnorm_kernel(
    const float* __restrict__ x, const float* __restrict__ w, float* __restrict__ o)
{
    int tok = blockIdx.x;
    const float* xr = x + (size_t)tok * DM;
    float ss = 0.f;
    for (int j = threadIdx.x; j < DM; j += 256) { float v = xr[j]; ss += v*v; }
    #pragma unroll
    for (int off = 32; off > 0; off >>= 1) ss += __shfl_down(ss, off);
    __shared__ float red[4];
    int lane = threadIdx.x & 63, wv = threadIdx.x >> 6;
    if (lane == 0) red[wv] = ss;
    __syncthreads();
    if (threadIdx.x == 0) {
        float t = red[0] + red[1] + red[2] + red[3];
        red[0] = rsqrtf(t / (float)DM + 1e-5f);
    }
    __syncthreads();
    float r = red[0];
    for (int j = threadIdx.x; j < DM; j += 256)
        o[(size_t)tok*DM + j] = xr[j] * w[j] * r;
}

// ---------------- generic tiled f32 GEMM: C[m,n] (+)= act( sum_k A[m,k]*W[n,k] + bias[n] ) ----------------
__global__ __launch_bounds__(256) void gemm_bt_kernel(
    const float* __restrict__ A, int lda,
    const float* __restrict__ W,
    const float* __restrict__ bias,
    float* __restrict__ C, int ldc,
    int M, int N, int K, int act, int accum)
{
    __shared__ float As[16][65];
    __shared__ float Ws[16][65];
    const int bm = blockIdx.y * 64;
    const int bn = blockIdx.x * 64;
    const int tid = threadIdx.x;
    const int tm = (tid >> 4) << 2;
    const int tn = (tid & 15) << 2;
    float acc[4][4] = {};
    for (int k0 = 0; k0 < K; k0 += 16) {
        #pragma unroll
        for (int i = 0; i < 4; ++i) {
            int idx = tid + i * 256;       // 0..1023
            int m  = idx >> 4;
            int kk = idx & 15;
            int gm = bm + m, gk = k0 + kk;
            As[kk][m] = (gm < M && gk < K) ? A[(size_t)gm*lda + gk] : 0.f;
            int gn = bn + m;
            Ws[kk][m] = (gn < N && gk < K) ? W[(size_t)gn*K + gk] : 0.f;
        }
        __syncthreads();
        #pragma unroll
        for (int kk = 0; kk < 16; ++kk) {
            float a[4], w[4];
            #pragma unroll
            for (int ii = 0; ii < 4; ++ii) a[ii] = As[kk][tm+ii];
            #pragma unroll
            for (int jj = 0; jj < 4; ++jj) w[jj] = Ws[kk][tn+jj];
            #pragma unroll
            for (int ii = 0; ii < 4; ++ii)
                #pragma unroll
                for (int jj = 0; jj < 4; ++jj)
                    acc[ii][jj] = fmaf(a[ii], w[jj], acc[ii][jj]);
        }
        __syncthreads();
    }
    #pragma unroll
    for (int ii = 0; ii < 4; ++ii) {
        int gm = bm + tm + ii;
        if (gm >= M) continue;
        #pragma unroll
        for (int jj = 0; jj < 4; ++jj) {
            int gn = bn + tn + jj;
            if (gn >= N) continue;
            float v = acc[ii][jj];
            if (bias) v += bias[gn];
            if (act == 1) v = (v > 20.f) ? v : log1pf(expf(v));
            size_t o = (size_t)gm*ldc + gn;
            if (accum) C[o] += v; else C[o] = v;
        }
    }
}

// ---------------- causal depthwise conv4 + bias + SiLU ----------------
__global__ __launch_bounds__(256) void conv_silu_kernel(
    const float* __restrict__ xz, const float* __restrict__ cw,
    const float* __restrict__ cb, float* __restrict__ u)
{
    int idx = blockIdx.x * 256 + threadIdx.x;
    if (idx >= BB*LL*DI) return;
    int d = idx % DI;
    int l = (idx / DI) % LL;
    int b = idx / (DI * LL);
    float acc = cb[d];
    #pragma unroll
    for (int k = 0; k < 4; ++k) {
        int ls = l - 3 + k;
        if (ls >= 0)
            acc = fmaf(xz[((size_t)(b*LL + ls))*(2*DI) + d], cw[d*4 + k], acc);
    }
    u[idx] = acc / (1.f + __expf(-acc));
}

// ================= chunk-parallel selective scan =================
// recurrence per (b,d,s): h_t = a_t*h_{t-1} + w_t,
//   a_t = exp(delta[t,d]*A[d,s]), w_t = delta[t,d]*u[t,d]*B[t,s]
// Phase A: per (b,chunk,d) compute P[s]=prod a, Hloc[s]=local scan (h_in=0)
__global__ __launch_bounds__(256) void scan_phaseA(
    const float* __restrict__ delta, const float* __restrict__ u,
    const float* __restrict__ dbl, const float* __restrict__ A_log,
    float* __restrict__ Psum, float* __restrict__ Hsum)
{
    const int d = blockIdx.x * 256 + threadIdx.x;   // 0..DI-1
    const int c = blockIdx.y;                        // chunk
    const int b = blockIdx.z;
    float A[DS], P[DS], hl[DS];
    #pragma unroll
    for (int s = 0; s < DS; ++s) {
        A[s] = -expf(A_log[(size_t)d*DS + s]);
        P[s] = 1.f; hl[s] = 0.f;
    }
    const int t0 = c * CT;
    for (int t = t0; t < t0 + CT; ++t) {
        const size_t row = (size_t)b*LL + t;
        const float* bc = dbl + row*WXROWS + DTR;
        float dt = delta[row*DI + d];
        float du = dt * u[row*DI + d];
        #pragma unroll
        for (int s = 0; s < DS; ++s) {
            float a = __expf(dt * A[s]);
            P[s] *= a;
            hl[s] = fmaf(a, hl[s], du * bc[s]);
        }
    }
    const size_t off = (((size_t)b*NC + c)*DI + d)*DS;
    #pragma unroll
    for (int s = 0; s < DS; ++s) { Psum[off+s] = P[s]; Hsum[off+s] = hl[s]; }
}

// Phase B: per (b,d,s) sequential prefix over NC chunk summaries -> carry-in Hin
__global__ __launch_bounds__(256) void scan_phaseB(
    const float* __restrict__ Psum, const float* __restrict__ Hsum,
    float* __restrict__ Hin)
{
    const int gid = blockIdx.x * 256 + threadIdx.x;  // 0 .. B*DI*DS-1
    if (gid >= BB*DI*DS) return;
    const int b = gid / (DI*DS);
    const int r = gid % (DI*DS);
    float hc = 0.f;
    for (int c = 0; c < NC; ++c) {
        const size_t off = ((size_t)(b*NC + c))*DI*DS + r;
        Hin[off] = hc;
        hc = fmaf(Psum[off], hc, Hsum[off]);
    }
}

// Phase C: rerun recurrence per chunk from Hin, produce gated output
// yfull[b,l,d] = ( y + u*Dsk ) * silu(z) ; written in-place over delta (safe)
__global__ __launch_bounds__(256) void scan_phaseC(
    const float* __restrict__ delta, const float* __restrict__ u,
    const float* __restrict__ dbl, const float* __restrict__ xz,
    const float* __restrict__ A_log, const float* __restrict__ Dsk,
    const float* __restrict__ Hin, float* __restrict__ yfull)
{
    const int d = blockIdx.x * 256 + threadIdx.x;
    const int c = blockIdx.y;
    const int b = blockIdx.z;
    float A[DS], h[DS];
    const size_t hoff = (((size_t)b*NC + c)*DI + d)*DS;
    #pragma unroll
    for (int s = 0; s < DS; ++s) {
        A[s] = -expf(A_log[(size_t)d*DS + s]);
        h[s] = Hin[hoff + s];
    }
    const float dsk = Dsk[d];
    const int t0 = c * CT;
    for (int t = t0; t < t0 + CT; ++t) {
        const size_t row = (size_t)b*LL + t;
        const float* bc = dbl + row*WXROWS + DTR;
        float dt = delta[row*DI + d];
        float ut = u[row*DI + d];
        float du = dt * ut;
        float y = 0.f;
        #pragma unroll
        for (int s = 0; s < DS; ++s) {
            float a = __expf(dt * A[s]);
            h[s] = fmaf(a, h[s], du * bc[s]);
            y = fmaf(h[s], bc[DS+s], y);
        }
        float zt = xz[row*(2*DI) + DI + d];
        float sz = zt / (1.f + __expf(-zt));
        yfull[row*DI + d] = (y + ut * dsk) * sz;
    }
}

// ---------------- final rmsnorm + gather last valid token ----------------
__global__ __launch_bounds__(256) void final_kernel(
    const float* __restrict__ h, const float* __restrict__ w,
    const int* __restrict__ lengths, float* __restrict__ out)
{
    int b = blockIdx.x;
    int idx = lengths[b] - 1;
    const float* xr = h + ((size_t)b*LL + idx)*DM;
    float ss = 0.f;
    for (int j = threadIdx.x; j < DM; j += 256) { float v = xr[j]; ss += v*v; }
    #pragma unroll
    for (int off = 32; off > 0; off >>= 1) ss += __shfl_down(ss, off);
    __shared__ float red[4];
    int lane = threadIdx.x & 63, wv = threadIdx.x >> 6;
    if (lane == 0) red[wv] = ss;
    __syncthreads();
    if (threadIdx.x == 0) {
        float t = red[0] + red[1] + red[2] + red[3];
        red[0] = rsqrtf(t / (float)DM + 1e-5f);
    }
    __syncthreads();
    float r = red[0];
    for (int j = threadIdx.x; j < DM; j += 256)
        out[(size_t)b*DM + j] = xr[j] * w[j] * r;
}

extern "C" void kernel_launch(void* const* d_in, const int* in_sizes, int n_in,
                              void* d_out, int out_size, void* d_ws, size_t ws_size,
                              hipStream_t stream)
{
    const float* batch   = (const float*)d_in[0];
    const void*  mask    = d_in[1];
    const float* norm_w  = (const float*)d_in[2];
    const float* W_in    = (const float*)d_in[3];
    const float* conv_w  = (const float*)d_in[4];
    const float* conv_b  = (const float*)d_in[5];
    const float* W_x     = (const float*)d_in[6];
    const float* W_dt    = (const float*)d_in[7];
    const float* b_dt    = (const float*)d_in[8];
    const float* A_log   = (const float*)d_in[9];
    const float* D_skip  = (const float*)d_in[10];
    const float* W_out   = (const float*)d_in[11];
    const float* normf_w = (const float*)d_in[12];
    float* out = (float*)d_out;

    // workspace layout (floats)
    float* ws    = (float*)d_ws;
    float* h     = ws;                         // 1,572,864
    float* xn    = h    + (size_t)NTOK*DM;     // 1,572,864
    float* xz    = xn   + (size_t)NTOK*DM;     // 6,291,456
    float* u     = xz   + (size_t)NTOK*2*DI;   // 3,145,728
    float* dbl   = u    + (size_t)NTOK*DI;     // 163,840
    float* delta = dbl  + (size_t)NTOK*WXROWS; // 3,145,728 (also yfull, in-place)
    float* Psum  = delta + (size_t)NTOK*DI;    // 1,572,864
    float* Hsum  = Psum + (size_t)BB*NC*DI*DS; // 1,572,864
    float* Hin   = Hsum + (size_t)BB*NC*DI*DS; // 1,572,864
    int*   lengths = (int*)(Hin + (size_t)BB*NC*DI*DS);

    transpose_in_kernel<<<(BB*LL*DM + 255)/256, 256, 0, stream>>>(batch, h);
    lengths_kernel<<<1, 64, 0, stream>>>(mask, lengths);

    for (int i = 0; i < NL; ++i) {
        const float* Wi   = W_in  + (size_t)i * 2*DI * DM;
        const float* cwi  = conv_w + (size_t)i * DI * DC;
        const float* cbi  = conv_b + (size_t)i * DI;
        const float* Wxi  = W_x   + (size_t)i * WXROWS * DI;
        const float* Wdti = W_dt  + (size_t)i * DI * DTR;
        const float* bdti = b_dt  + (size_t)i * DI;
        const float* Ali  = A_log + (size_t)i * DI * DS;
        const float* Dski = D_skip + (size_t)i * DI;
        const float* Woi  = W_out + (size_t)i * DM * DI;

        rmsnorm_kernel<<<NTOK, 256, 0, stream>>>(h, norm_w + (size_t)i*DM, xn);
        gemm_bt_kernel<<<dim3((2*DI+63)/64, (NTOK+63)/64), 256, 0, stream>>>(
            xn, DM, Wi, nullptr, xz, 2*DI, NTOK, 2*DI, DM, 0, 0);
        conv_silu_kernel<<<(BB*LL*DI + 255)/256, 256, 0, stream>>>(xz, cwi, cbi, u);
        gemm_bt_kernel<<<dim3((WXROWS+63)/64, (NTOK+63)/64), 256, 0, stream>>>(
            u, DI, Wxi, nullptr, dbl, WXROWS, NTOK, WXROWS, DI, 0, 0);
        gemm_bt_kernel<<<dim3((DI+63)/64, (NTOK+63)/64), 256, 0, stream>>>(
            dbl, WXROWS, Wdti, bdti, delta, DI, NTOK, DI, DTR, 1, 0);

        // chunk-parallel scan
        scan_phaseA<<<dim3(DI/256, NC, BB), 256, 0, stream>>>(
            delta, u, dbl, Ali, Psum, Hsum);
        scan_phaseB<<<(BB*DI*DS + 255)/256, 256, 0, stream>>>(Psum, Hsum, Hin);
        scan_phaseC<<<dim3(DI/256, NC, BB), 256, 0, stream>>>(
            delta, u, dbl, xz, Ali, Dski, Hin, delta);

        gemm_bt_kernel<<<dim3((DM+63)/64, (NTOK+63)/64), 256, 0, stream>>>(
            delta, DI, Woi, nullptr, h, DM, NTOK, DM, DI, 0, 1);
    }

    final_kernel<<<BB, 256, 0, stream>>>(h, normf_w, lengths, out);
}

// Round 3
// 3185.575 us; speedup vs baseline: 4.5783x; 1.9153x over previous
//
#include <hip/hip_runtime.h>
#include <hip/hip_bf16.h>
#include <math.h>

// Problem dims (fixed)
#define BB 2
#define LL 1024
#define DM 768
#define NL 8
#define DS 16
#define DC 4
#define DI 1536
#define DTR 48
#define NTOK (BB*LL)          // 2048
#define WXROWS (DTR + 2*DS)   // 80
#define NC 32                 // scan chunks
#define CT (LL/NC)            // 32 timesteps per chunk

typedef __attribute__((ext_vector_type(8))) short bf16x8;
typedef __attribute__((ext_vector_type(4))) float f32x4;

__device__ inline void gload_lds16(const void* g, void* l) {
    __builtin_amdgcn_global_load_lds(
        (const __attribute__((address_space(1))) unsigned int*)g,
        (__attribute__((address_space(3))) unsigned int*)l, 16, 0, 0);
}

// ---------------- transpose input: batch[b,d,l] -> h[b,l,d] ----------------
__global__ __launch_bounds__(256) void transpose_in_kernel(
    const float* __restrict__ batch, float* __restrict__ h)
{
    int idx = blockIdx.x * 256 + threadIdx.x;
    if (idx >= BB*LL*DM) return;
    int d = idx % DM;
    int l = (idx / DM) % LL;
    int b = idx / (DM * LL);
    h[idx] = batch[((size_t)b*DM + d)*LL + l];
}

// ---------------- lengths from mask (robust to bool vs int32) ----------------
__global__ void lengths_kernel(const void* __restrict__ mask, int* __restrict__ lengths)
{
    int b = threadIdx.x;
    if (b >= BB) return;
    const unsigned int* mi = (const unsigned int*)mask;
    bool packed = (mi[0] == 0x01010101u);
    int cnt = 0;
    if (packed) {
        const unsigned char* mb = (const unsigned char*)mask;
        for (int i = 0; i < LL; ++i) cnt += (mb[(size_t)b*LL + i] != 0);
    } else {
        for (int i = 0; i < LL; ++i) cnt += (mi[(size_t)b*LL + i] != 0);
    }
    lengths[b] = cnt;
}

// ---------------- f32 -> bf16 conversion (4 elems/thread) ----------------
__global__ __launch_bounds__(256) void cvt_bf16_kernel(
    const float* __restrict__ in, __hip_bfloat16* __restrict__ o, int n)
{
    int i = (blockIdx.x * 256 + threadIdx.x) * 4;
    if (i >= n) return;
    float4 v = *(const float4*)(in + i);
    __hip_bfloat16 h0 = __float2bfloat16(v.x);
    __hip_bfloat16 h1 = __float2bfloat16(v.y);
    __hip_bfloat16 h2 = __float2bfloat16(v.z);
    __hip_bfloat16 h3 = __float2bfloat16(v.w);
    ushort4 r;
    r.x = *(unsigned short*)&h0; r.y = *(unsigned short*)&h1;
    r.z = *(unsigned short*)&h2; r.w = *(unsigned short*)&h3;
    *(ushort4*)(o + i) = r;
}

// ---------------- RMSNorm (per token, D=768) -> bf16 out ----------------
__global__ __launch_bounds__(256) void rmsnorm_kernel(
    const float* __restrict__ x, const float* __restrict__ w,
    __hip_bfloat16* __restrict__ o)
{
    int tok = blockIdx.x;
    const float* xr = x + (size_t)tok * DM;
    float ss = 0.f;
    for (int j = threadIdx.x; j < DM; j += 256) { float v = xr[j]; ss += v*v; }
    #pragma unroll
    for (int off = 32; off > 0; off >>= 1) ss += __shfl_down(ss, off);
    __shared__ float red[4];
    int lane = threadIdx.x & 63, wv = threadIdx.x >> 6;
    if (lane == 0) red[wv] = ss;
    __syncthreads();
    if (threadIdx.x == 0) {
        float t = red[0] + red[1] + red[2] + red[3];
        red[0] = rsqrtf(t / (float)DM + 1e-5f);
    }
    __syncthreads();
    float r = red[0];
    for (int j = threadIdx.x; j < DM; j += 256)
        o[(size_t)tok*DM + j] = __float2bfloat16(xr[j] * w[j] * r);
}

// ---------------- MFMA bf16 GEMM: C[m,n] (+)= sum_k A[m,k]*W[n,k] ----------------
// A:[M,K] bf16, W:[N,K] bf16 (both lda==K), C:[M,N] f32. 128x128 tile, BK=32, 4 waves.
template<int ACCUM>
__global__ __launch_bounds__(256) void gemm_mfma_kernel(
    const __hip_bfloat16* __restrict__ A,
    const __hip_bfloat16* __restrict__ W,
    float* __restrict__ C,
    int M, int N, int K)
{
    __shared__ short As[128*32];
    __shared__ short Ws[128*32];
    const int bm = blockIdx.y * 128;
    const int bn = blockIdx.x * 128;
    const int t = threadIdx.x;
    const int w = t >> 6;
    const int lane = t & 63;
    const int wr = w >> 1, wc = w & 1;       // 2x2 wave grid, 64x64 per wave
    const int fr = lane & 15;
    const int khi = lane >> 4;

    f32x4 acc[4][4];
    #pragma unroll
    for (int mi = 0; mi < 4; ++mi)
        #pragma unroll
        for (int ni = 0; ni < 4; ++ni)
            acc[mi][ni] = (f32x4){0.f, 0.f, 0.f, 0.f};

    // staging addresses: thread t loads 16B at LDS byte t*16 (per 4KB pass)
    const int rowL = t >> 2;                 // 0..63
    const int ks = (t & 3) * 8;              // k element offset of the 16B
    const __hip_bfloat16* gA0 = A + (size_t)(bm + rowL) * K + ks;
    const __hip_bfloat16* gA1 = A + (size_t)(bm + 64 + rowL) * K + ks;
    const __hip_bfloat16* gW0 = W + (size_t)(bn + rowL) * K + ks;
    const __hip_bfloat16* gW1 = W + (size_t)(bn + 64 + rowL) * K + ks;
    short* AsW = As + w * 512;               // wave-uniform LDS base (bytes w*1024)
    short* WsW = Ws + w * 512;

    for (int k0 = 0; k0 < K; k0 += 32) {
        gload_lds16(gA0 + k0, AsW);
        gload_lds16(gA1 + k0, AsW + 2048);
        gload_lds16(gW0 + k0, WsW);
        gload_lds16(gW1 + k0, WsW + 2048);
        asm volatile("s_waitcnt vmcnt(0)" ::: "memory");
        __syncthreads();
        bf16x8 a[4], b[4];
        #pragma unroll
        for (int mi = 0; mi < 4; ++mi)
            a[mi] = *(const bf16x8*)&As[(wr*64 + mi*16 + fr)*32 + khi*8];
        #pragma unroll
        for (int ni = 0; ni < 4; ++ni)
            b[ni] = *(const bf16x8*)&Ws[(wc*64 + ni*16 + fr)*32 + khi*8];
        #pragma unroll
        for (int mi = 0; mi < 4; ++mi)
            #pragma unroll
            for (int ni = 0; ni < 4; ++ni)
                acc[mi][ni] = __builtin_amdgcn_mfma_f32_16x16x32_bf16(
                    a[mi], b[ni], acc[mi][ni], 0, 0, 0);
        __syncthreads();
    }

    #pragma unroll
    for (int mi = 0; mi < 4; ++mi) {
        #pragma unroll
        for (int ni = 0; ni < 4; ++ni) {
            int gc = bn + wc*64 + ni*16 + fr;
            #pragma unroll
            for (int r = 0; r < 4; ++r) {
                int gr = bm + wr*64 + mi*16 + khi*4 + r;
                size_t o = (size_t)gr * N + gc;
                if (ACCUM) C[o] += acc[mi][ni][r];
                else       C[o]  = acc[mi][ni][r];
            }
        }
    }
}

// ---------------- generic tiled f32 GEMM (small shapes) ----------------
__global__ __launch_bounds__(256) void gemm_bt_kernel(
    const float* __restrict__ A, int lda,
    const float* __restrict__ W,
    const float* __restrict__ bias,
    float* __restrict__ C, int ldc,
    int M, int N, int K, int act, int accum)
{
    __shared__ float As[16][65];
    __shared__ float Ws[16][65];
    const int bm = blockIdx.y * 64;
    const int bn = blockIdx.x * 64;
    const int tid = threadIdx.x;
    const int tm = (tid >> 4) << 2;
    const int tn = (tid & 15) << 2;
    float acc[4][4] = {};
    for (int k0 = 0; k0 < K; k0 += 16) {
        #pragma unroll
        for (int i = 0; i < 4; ++i) {
            int idx = tid + i * 256;
            int m  = idx >> 4;
            int kk = idx & 15;
            int gm = bm + m, gk = k0 + kk;
            As[kk][m] = (gm < M && gk < K) ? A[(size_t)gm*lda + gk] : 0.f;
            int gn = bn + m;
            Ws[kk][m] = (gn < N && gk < K) ? W[(size_t)gn*K + gk] : 0.f;
        }
        __syncthreads();
        #pragma unroll
        for (int kk = 0; kk < 16; ++kk) {
            float a[4], w[4];
            #pragma unroll
            for (int ii = 0; ii < 4; ++ii) a[ii] = As[kk][tm+ii];
            #pragma unroll
            for (int jj = 0; jj < 4; ++jj) w[jj] = Ws[kk][tn+jj];
            #pragma unroll
            for (int ii = 0; ii < 4; ++ii)
                #pragma unroll
                for (int jj = 0; jj < 4; ++jj)
                    acc[ii][jj] = fmaf(a[ii], w[jj], acc[ii][jj]);
        }
        __syncthreads();
    }
    #pragma unroll
    for (int ii = 0; ii < 4; ++ii) {
        int gm = bm + tm + ii;
        if (gm >= M) continue;
        #pragma unroll
        for (int jj = 0; jj < 4; ++jj) {
            int gn = bn + tn + jj;
            if (gn >= N) continue;
            float v = acc[ii][jj];
            if (bias) v += bias[gn];
            if (act == 1) v = (v > 20.f) ? v : log1pf(expf(v));
            size_t o = (size_t)gm*ldc + gn;
            if (accum) C[o] += v; else C[o] = v;
        }
    }
}

// ---------------- causal depthwise conv4 + bias + SiLU ----------------
__global__ __launch_bounds__(256) void conv_silu_kernel(
    const float* __restrict__ xz, const float* __restrict__ cw,
    const float* __restrict__ cb, float* __restrict__ u)
{
    int idx = blockIdx.x * 256 + threadIdx.x;
    if (idx >= BB*LL*DI) return;
    int d = idx % DI;
    int l = (idx / DI) % LL;
    int b = idx / (DI * LL);
    float acc = cb[d];
    #pragma unroll
    for (int k = 0; k < 4; ++k) {
        int ls = l - 3 + k;
        if (ls >= 0)
            acc = fmaf(xz[((size_t)(b*LL + ls))*(2*DI) + d], cw[d*4 + k], acc);
    }
    u[idx] = acc / (1.f + __expf(-acc));
}

// ================= chunk-parallel selective scan =================
__global__ __launch_bounds__(256) void scan_phaseA(
    const float* __restrict__ delta, const float* __restrict__ u,
    const float* __restrict__ dbl, const float* __restrict__ A_log,
    float* __restrict__ Psum, float* __restrict__ Hsum)
{
    const int d = blockIdx.x * 256 + threadIdx.x;
    const int c = blockIdx.y;
    const int b = blockIdx.z;
    float A[DS], P[DS], hl[DS];
    #pragma unroll
    for (int s = 0; s < DS; ++s) {
        A[s] = -expf(A_log[(size_t)d*DS + s]);
        P[s] = 1.f; hl[s] = 0.f;
    }
    const int t0 = c * CT;
    for (int t = t0; t < t0 + CT; ++t) {
        const size_t row = (size_t)b*LL + t;
        const float* bc = dbl + row*WXROWS + DTR;
        float dt = delta[row*DI + d];
        float du = dt * u[row*DI + d];
        #pragma unroll
        for (int s = 0; s < DS; ++s) {
            float a = __expf(dt * A[s]);
            P[s] *= a;
            hl[s] = fmaf(a, hl[s], du * bc[s]);
        }
    }
    const size_t off = (((size_t)b*NC + c)*DI + d)*DS;
    #pragma unroll
    for (int s = 0; s < DS; ++s) { Psum[off+s] = P[s]; Hsum[off+s] = hl[s]; }
}

__global__ __launch_bounds__(256) void scan_phaseB(
    const float* __restrict__ Psum, const float* __restrict__ Hsum,
    float* __restrict__ Hin)
{
    const int gid = blockIdx.x * 256 + threadIdx.x;
    if (gid >= BB*DI*DS) return;
    const int b = gid / (DI*DS);
    const int r = gid % (DI*DS);
    float hc = 0.f;
    for (int c = 0; c < NC; ++c) {
        const size_t off = ((size_t)(b*NC + c))*DI*DS + r;
        Hin[off] = hc;
        hc = fmaf(Psum[off], hc, Hsum[off]);
    }
}

// Phase C: rerun recurrence from Hin, gated output -> bf16
__global__ __launch_bounds__(256) void scan_phaseC(
    const float* __restrict__ delta, const float* __restrict__ u,
    const float* __restrict__ dbl, const float* __restrict__ xz,
    const float* __restrict__ A_log, const float* __restrict__ Dsk,
    const float* __restrict__ Hin, __hip_bfloat16* __restrict__ yfull)
{
    const int d = blockIdx.x * 256 + threadIdx.x;
    const int c = blockIdx.y;
    const int b = blockIdx.z;
    float A[DS], h[DS];
    const size_t hoff = (((size_t)b*NC + c)*DI + d)*DS;
    #pragma unroll
    for (int s = 0; s < DS; ++s) {
        A[s] = -expf(A_log[(size_t)d*DS + s]);
        h[s] = Hin[hoff + s];
    }
    const float dsk = Dsk[d];
    const int t0 = c * CT;
    for (int t = t0; t < t0 + CT; ++t) {
        const size_t row = (size_t)b*LL + t;
        const float* bc = dbl + row*WXROWS + DTR;
        float dt = delta[row*DI + d];
        float ut = u[row*DI + d];
        float du = dt * ut;
        float y = 0.f;
        #pragma unroll
        for (int s = 0; s < DS; ++s) {
            float a = __expf(dt * A[s]);
            h[s] = fmaf(a, h[s], du * bc[s]);
            y = fmaf(h[s], bc[DS+s], y);
        }
        float zt = xz[row*(2*DI) + DI + d];
        float sz = zt / (1.f + __expf(-zt));
        yfull[row*DI + d] = __float2bfloat16((y + ut * dsk) * sz);
    }
}

// ---------------- final rmsnorm + gather last valid token ----------------
__global__ __launch_bounds__(256) void final_kernel(
    const float* __restrict__ h, const float* __restrict__ w,
    const int* __restrict__ lengths, float* __restrict__ out)
{
    int b = blockIdx.x;
    int idx = lengths[b] - 1;
    const float* xr = h + ((size_t)b*LL + idx)*DM;
    float ss = 0.f;
    for (int j = threadIdx.x; j < DM; j += 256) { float v = xr[j]; ss += v*v; }
    #pragma unroll
    for (int off = 32; off > 0; off >>= 1) ss += __shfl_down(ss, off);
    __shared__ float red[4];
    int lane = threadIdx.x & 63, wv = threadIdx.x >> 6;
    if (lane == 0) red[wv] = ss;
    __syncthreads();
    if (threadIdx.x == 0) {
        float t = red[0] + red[1] + red[2] + red[3];
        red[0] = rsqrtf(t / (float)DM + 1e-5f);
    }
    __syncthreads();
    float r = red[0];
    for (int j = threadIdx.x; j < DM; j += 256)
        out[(size_t)b*DM + j] = xr[j] * w[j] * r;
}

extern "C" void kernel_launch(void* const* d_in, const int* in_sizes, int n_in,
                              void* d_out, int out_size, void* d_ws, size_t ws_size,
                              hipStream_t stream)
{
    const float* batch   = (const float*)d_in[0];
    const void*  mask    = d_in[1];
    const float* norm_w  = (const float*)d_in[2];
    const float* W_in    = (const float*)d_in[3];
    const float* conv_w  = (const float*)d_in[4];
    const float* conv_b  = (const float*)d_in[5];
    const float* W_x     = (const float*)d_in[6];
    const float* W_dt    = (const float*)d_in[7];
    const float* b_dt    = (const float*)d_in[8];
    const float* A_log   = (const float*)d_in[9];
    const float* D_skip  = (const float*)d_in[10];
    const float* W_out   = (const float*)d_in[11];
    const float* normf_w = (const float*)d_in[12];
    float* out = (float*)d_out;

    // workspace layout
    float* ws    = (float*)d_ws;
    float* h     = ws;                         // 1,572,864 f32
    float* xz    = h    + (size_t)NTOK*DM;     // 6,291,456 f32
    float* u     = xz   + (size_t)NTOK*2*DI;   // 3,145,728 f32
    float* dbl   = u    + (size_t)NTOK*DI;     //   163,840 f32
    float* delta = dbl  + (size_t)NTOK*WXROWS; // 3,145,728 f32
    float* Psum  = delta + (size_t)NTOK*DI;    // 1,572,864 f32
    float* Hsum  = Psum + (size_t)BB*NC*DI*DS; // 1,572,864 f32
    float* Hin   = Hsum + (size_t)BB*NC*DI*DS; // 1,572,864 f32
    __hip_bfloat16* xn_bf  = (__hip_bfloat16*)(Hin + (size_t)BB*NC*DI*DS); // 1,572,864 bf16
    __hip_bfloat16* y_bf   = xn_bf + (size_t)NTOK*DM;                      // 3,145,728 bf16
    __hip_bfloat16* Win_bf = y_bf + (size_t)NTOK*DI;                       // 2,359,296 bf16
    __hip_bfloat16* Wout_bf= Win_bf + (size_t)2*DI*DM;                     // 1,179,648 bf16
    int*   lengths = (int*)(Wout_bf + (size_t)DM*DI);

    transpose_in_kernel<<<(BB*LL*DM + 255)/256, 256, 0, stream>>>(batch, h);
    lengths_kernel<<<1, 64, 0, stream>>>(mask, lengths);

    for (int i = 0; i < NL; ++i) {
        const float* Wi   = W_in  + (size_t)i * 2*DI * DM;
        const float* cwi  = conv_w + (size_t)i * DI * DC;
        const float* cbi  = conv_b + (size_t)i * DI;
        const float* Wxi  = W_x   + (size_t)i * WXROWS * DI;
        const float* Wdti = W_dt  + (size_t)i * DI * DTR;
        const float* bdti = b_dt  + (size_t)i * DI;
        const float* Ali  = A_log + (size_t)i * DI * DS;
        const float* Dski = D_skip + (size_t)i * DI;
        const float* Woi  = W_out + (size_t)i * DM * DI;

        // weight slices -> bf16
        cvt_bf16_kernel<<<(2*DI*DM/4 + 255)/256, 256, 0, stream>>>(Wi, Win_bf, 2*DI*DM);
        cvt_bf16_kernel<<<(DM*DI/4 + 255)/256, 256, 0, stream>>>(Woi, Wout_bf, DM*DI);

        // 1) pre-norm -> bf16
        rmsnorm_kernel<<<NTOK, 256, 0, stream>>>(h, norm_w + (size_t)i*DM, xn_bf);
        // 2) xz = xn @ W_in^T  (MFMA)  [2048 x 3072], K=768
        gemm_mfma_kernel<0><<<dim3(2*DI/128, NTOK/128), 256, 0, stream>>>(
            xn_bf, Win_bf, xz, NTOK, 2*DI, DM);
        // 3) causal conv + SiLU -> u
        conv_silu_kernel<<<(BB*LL*DI + 255)/256, 256, 0, stream>>>(xz, cwi, cbi, u);
        // 4) dbl = u @ W_x^T  [2048 x 80] (f32)
        gemm_bt_kernel<<<dim3((WXROWS+63)/64, (NTOK+63)/64), 256, 0, stream>>>(
            u, DI, Wxi, nullptr, dbl, WXROWS, NTOK, WXROWS, DI, 0, 0);
        // 5) delta = softplus(dtp @ W_dt^T + b_dt)  [2048 x 1536] (f32)
        gemm_bt_kernel<<<dim3((DI+63)/64, (NTOK+63)/64), 256, 0, stream>>>(
            dbl, WXROWS, Wdti, bdti, delta, DI, NTOK, DI, DTR, 1, 0);

        // chunk-parallel scan
        scan_phaseA<<<dim3(DI/256, NC, BB), 256, 0, stream>>>(
            delta, u, dbl, Ali, Psum, Hsum);
        scan_phaseB<<<(BB*DI*DS + 255)/256, 256, 0, stream>>>(Psum, Hsum, Hin);
        scan_phaseC<<<dim3(DI/256, NC, BB), 256, 0, stream>>>(
            delta, u, dbl, xz, Ali, Dski, Hin, y_bf);

        // 7) h += y @ W_out^T  (MFMA)  [2048 x 768], K=1536
        gemm_mfma_kernel<1><<<dim3(DM/128, NTOK/128), 256, 0, stream>>>(
            y_bf, Wout_bf, h, NTOK, DM, DI);
    }

    final_kernel<<<BB, 256, 0, stream>>>(h, normf_w, lengths, out);
}

// Round 4
// 1523.993 us; speedup vs baseline: 9.5700x; 2.0903x over previous
//
#include <hip/hip_runtime.h>
#include <hip/hip_bf16.h>
#include <math.h>

// Problem dims (fixed)
#define BB 2
#define LL 1024
#define DM 768
#define NL 8
#define DS 16
#define DC 4
#define DI 1536
#define DTR 48
#define NTOK (BB*LL)          // 2048
#define WXROWS (DTR + 2*DS)   // 80
#define NC 32                 // scan chunks
#define CT (LL/NC)            // 32 timesteps per chunk
#define SKS 8                 // split-K for W_x GEMM
#define SKC (DI/SKS)          // 192 per split

typedef __attribute__((ext_vector_type(8))) short bf16x8;
typedef __attribute__((ext_vector_type(4))) float f32x4;

__device__ inline void gload_lds16(const void* g, void* l) {
    __builtin_amdgcn_global_load_lds(
        (const __attribute__((address_space(1))) unsigned int*)g,
        (__attribute__((address_space(3))) unsigned int*)l, 16, 0, 0);
}

// ---------------- transpose input: batch[b,d,l] -> h[b,l,d] ----------------
__global__ __launch_bounds__(256) void transpose_in_kernel(
    const float* __restrict__ batch, float* __restrict__ h)
{
    int idx = blockIdx.x * 256 + threadIdx.x;
    if (idx >= BB*LL*DM) return;
    int d = idx % DM;
    int l = (idx / DM) % LL;
    int b = idx / (DM * LL);
    h[idx] = batch[((size_t)b*DM + d)*LL + l];
}

// ---------------- lengths from mask (robust to bool vs int32) ----------------
__global__ void lengths_kernel(const void* __restrict__ mask, int* __restrict__ lengths)
{
    int b = threadIdx.x;
    if (b >= BB) return;
    const unsigned int* mi = (const unsigned int*)mask;
    bool packed = (mi[0] == 0x01010101u);
    int cnt = 0;
    if (packed) {
        const unsigned char* mb = (const unsigned char*)mask;
        for (int i = 0; i < LL; ++i) cnt += (mb[(size_t)b*LL + i] != 0);
    } else {
        for (int i = 0; i < LL; ++i) cnt += (mi[(size_t)b*LL + i] != 0);
    }
    lengths[b] = cnt;
}

// ---------------- f32 -> bf16 conversion (4 elems/thread) ----------------
__global__ __launch_bounds__(256) void cvt_bf16_kernel(
    const float* __restrict__ in, __hip_bfloat16* __restrict__ o, int n)
{
    int i = (blockIdx.x * 256 + threadIdx.x) * 4;
    if (i >= n) return;
    float4 v = *(const float4*)(in + i);
    __hip_bfloat16 h0 = __float2bfloat16(v.x);
    __hip_bfloat16 h1 = __float2bfloat16(v.y);
    __hip_bfloat16 h2 = __float2bfloat16(v.z);
    __hip_bfloat16 h3 = __float2bfloat16(v.w);
    ushort4 r;
    r.x = *(unsigned short*)&h0; r.y = *(unsigned short*)&h1;
    r.z = *(unsigned short*)&h2; r.w = *(unsigned short*)&h3;
    *(ushort4*)(o + i) = r;
}

// f32 -> bf16 with zero-padding beyond n_src (n_tot elements written)
__global__ __launch_bounds__(256) void cvt_pad_bf16_kernel(
    const float* __restrict__ in, __hip_bfloat16* __restrict__ o,
    int n_src, int n_tot)
{
    int i = (blockIdx.x * 256 + threadIdx.x) * 4;
    if (i >= n_tot) return;
    ushort4 r = {0, 0, 0, 0};
    if (i + 3 < n_src) {
        float4 v = *(const float4*)(in + i);
        __hip_bfloat16 h0 = __float2bfloat16(v.x);
        __hip_bfloat16 h1 = __float2bfloat16(v.y);
        __hip_bfloat16 h2 = __float2bfloat16(v.z);
        __hip_bfloat16 h3 = __float2bfloat16(v.w);
        r.x = *(unsigned short*)&h0; r.y = *(unsigned short*)&h1;
        r.z = *(unsigned short*)&h2; r.w = *(unsigned short*)&h3;
    }
    *(ushort4*)(o + i) = r;
}

// ---------------- RMSNorm (per token, D=768) -> bf16 out ----------------
__global__ __launch_bounds__(256) void rmsnorm_kernel(
    const float* __restrict__ x, const float* __restrict__ w,
    __hip_bfloat16* __restrict__ o)
{
    int tok = blockIdx.x;
    const float* xr = x + (size_t)tok * DM;
    float ss = 0.f;
    for (int j = threadIdx.x; j < DM; j += 256) { float v = xr[j]; ss += v*v; }
    #pragma unroll
    for (int off = 32; off > 0; off >>= 1) ss += __shfl_down(ss, off);
    __shared__ float red[4];
    int lane = threadIdx.x & 63, wv = threadIdx.x >> 6;
    if (lane == 0) red[wv] = ss;
    __syncthreads();
    if (threadIdx.x == 0) {
        float t = red[0] + red[1] + red[2] + red[3];
        red[0] = rsqrtf(t / (float)DM + 1e-5f);
    }
    __syncthreads();
    float r = red[0];
    for (int j = threadIdx.x; j < DM; j += 256)
        o[(size_t)tok*DM + j] = __float2bfloat16(xr[j] * w[j] * r);
}

// ---------------- MFMA bf16 GEMM: C[m,n] (+)= sum_k A[m,k]*W[n,k] ----------------
// A:[M,K] bf16, W:[N,K] bf16 (both lda==K), C:[M,N] f32. 128x128 tile, BK=32, 4 waves.
template<int ACCUM>
__global__ __launch_bounds__(256) void gemm_mfma_kernel(
    const __hip_bfloat16* __restrict__ A,
    const __hip_bfloat16* __restrict__ W,
    float* __restrict__ C,
    int M, int N, int K)
{
    __shared__ short As[128*32];
    __shared__ short Ws[128*32];
    const int bm = blockIdx.y * 128;
    const int bn = blockIdx.x * 128;
    const int t = threadIdx.x;
    const int w = t >> 6;
    const int lane = t & 63;
    const int wr = w >> 1, wc = w & 1;       // 2x2 wave grid, 64x64 per wave
    const int fr = lane & 15;
    const int khi = lane >> 4;

    f32x4 acc[4][4];
    #pragma unroll
    for (int mi = 0; mi < 4; ++mi)
        #pragma unroll
        for (int ni = 0; ni < 4; ++ni)
            acc[mi][ni] = (f32x4){0.f, 0.f, 0.f, 0.f};

    const int rowL = t >> 2;                 // 0..63
    const int ks = (t & 3) * 8;
    const __hip_bfloat16* gA0 = A + (size_t)(bm + rowL) * K + ks;
    const __hip_bfloat16* gA1 = A + (size_t)(bm + 64 + rowL) * K + ks;
    const __hip_bfloat16* gW0 = W + (size_t)(bn + rowL) * K + ks;
    const __hip_bfloat16* gW1 = W + (size_t)(bn + 64 + rowL) * K + ks;
    short* AsW = As + w * 512;
    short* WsW = Ws + w * 512;

    for (int k0 = 0; k0 < K; k0 += 32) {
        gload_lds16(gA0 + k0, AsW);
        gload_lds16(gA1 + k0, AsW + 2048);
        gload_lds16(gW0 + k0, WsW);
        gload_lds16(gW1 + k0, WsW + 2048);
        asm volatile("s_waitcnt vmcnt(0)" ::: "memory");
        __syncthreads();
        bf16x8 a[4], b[4];
        #pragma unroll
        for (int mi = 0; mi < 4; ++mi)
            a[mi] = *(const bf16x8*)&As[(wr*64 + mi*16 + fr)*32 + khi*8];
        #pragma unroll
        for (int ni = 0; ni < 4; ++ni)
            b[ni] = *(const bf16x8*)&Ws[(wc*64 + ni*16 + fr)*32 + khi*8];
        #pragma unroll
        for (int mi = 0; mi < 4; ++mi)
            #pragma unroll
            for (int ni = 0; ni < 4; ++ni)
                acc[mi][ni] = __builtin_amdgcn_mfma_f32_16x16x32_bf16(
                    a[mi], b[ni], acc[mi][ni], 0, 0, 0);
        __syncthreads();
    }

    #pragma unroll
    for (int mi = 0; mi < 4; ++mi) {
        #pragma unroll
        for (int ni = 0; ni < 4; ++ni) {
            int gc = bn + wc*64 + ni*16 + fr;
            #pragma unroll
            for (int r = 0; r < 4; ++r) {
                int gr = bm + wr*64 + mi*16 + khi*4 + r;
                size_t o = (size_t)gr * N + gc;
                if (ACCUM) C[o] += acc[mi][ni][r];
                else       C[o]  = acc[mi][ni][r];
            }
        }
    }
}

// ---------------- skinny MFMA split-K GEMM: dblp[split][m][0..79] ----------------
// A: u_bf [NTOK, DI], W: Wxpad [128, DI] (rows 80..127 zero), partials f32.
__global__ __launch_bounds__(256) void gemm_mfma_skinny(
    const __hip_bfloat16* __restrict__ A,
    const __hip_bfloat16* __restrict__ W,
    float* __restrict__ Cp)
{
    __shared__ short As[128*32];
    __shared__ short Ws[128*32];
    const int split = blockIdx.x;            // 0..SKS-1
    const int bm = blockIdx.y * 128;
    const int t = threadIdx.x;
    const int w = t >> 6;
    const int lane = t & 63;
    const int wr = w >> 1, wc = w & 1;
    const int fr = lane & 15;
    const int khi = lane >> 4;

    f32x4 acc[4][4];
    #pragma unroll
    for (int mi = 0; mi < 4; ++mi)
        #pragma unroll
        for (int ni = 0; ni < 4; ++ni)
            acc[mi][ni] = (f32x4){0.f, 0.f, 0.f, 0.f};

    const int rowL = t >> 2;
    const int ks = (t & 3) * 8;
    const __hip_bfloat16* gA0 = A + (size_t)(bm + rowL) * DI + ks;
    const __hip_bfloat16* gA1 = A + (size_t)(bm + 64 + rowL) * DI + ks;
    const __hip_bfloat16* gW0 = W + (size_t)rowL * DI + ks;
    const __hip_bfloat16* gW1 = W + (size_t)(64 + rowL) * DI + ks;
    short* AsW = As + w * 512;
    short* WsW = Ws + w * 512;

    const int kbeg = split * SKC;
    for (int k0 = kbeg; k0 < kbeg + SKC; k0 += 32) {
        gload_lds16(gA0 + k0, AsW);
        gload_lds16(gA1 + k0, AsW + 2048);
        gload_lds16(gW0 + k0, WsW);
        gload_lds16(gW1 + k0, WsW + 2048);
        asm volatile("s_waitcnt vmcnt(0)" ::: "memory");
        __syncthreads();
        bf16x8 a[4], b[4];
        #pragma unroll
        for (int mi = 0; mi < 4; ++mi)
            a[mi] = *(const bf16x8*)&As[(wr*64 + mi*16 + fr)*32 + khi*8];
        #pragma unroll
        for (int ni = 0; ni < 4; ++ni)
            b[ni] = *(const bf16x8*)&Ws[(wc*64 + ni*16 + fr)*32 + khi*8];
        #pragma unroll
        for (int mi = 0; mi < 4; ++mi)
            #pragma unroll
            for (int ni = 0; ni < 4; ++ni)
                acc[mi][ni] = __builtin_amdgcn_mfma_f32_16x16x32_bf16(
                    a[mi], b[ni], acc[mi][ni], 0, 0, 0);
        __syncthreads();
    }

    #pragma unroll
    for (int mi = 0; mi < 4; ++mi) {
        #pragma unroll
        for (int ni = 0; ni < 4; ++ni) {
            int gc = wc*64 + ni*16 + fr;
            if (gc >= WXROWS) continue;
            #pragma unroll
            for (int r = 0; r < 4; ++r) {
                int gr = bm + wr*64 + mi*16 + khi*4 + r;
                Cp[((size_t)split*NTOK + gr)*WXROWS + gc] = acc[mi][ni][r];
            }
        }
    }
}

// reduce split-K partials -> dbl [NTOK,80]
__global__ __launch_bounds__(256) void reduce_dbl_kernel(
    const float* __restrict__ Cp, float* __restrict__ dbl)
{
    int i = blockIdx.x * 256 + threadIdx.x;  // < NTOK*WXROWS
    float s = 0.f;
    #pragma unroll
    for (int p = 0; p < SKS; ++p) s += Cp[(size_t)p*NTOK*WXROWS + i];
    dbl[i] = s;
}

// ---------------- generic tiled f32 GEMM (small shapes) ----------------
__global__ __launch_bounds__(256) void gemm_bt_kernel(
    const float* __restrict__ A, int lda,
    const float* __restrict__ W,
    const float* __restrict__ bias,
    float* __restrict__ C, int ldc,
    int M, int N, int K, int act, int accum)
{
    __shared__ float As[16][65];
    __shared__ float Ws[16][65];
    const int bm = blockIdx.y * 64;
    const int bn = blockIdx.x * 64;
    const int tid = threadIdx.x;
    const int tm = (tid >> 4) << 2;
    const int tn = (tid & 15) << 2;
    float acc[4][4] = {};
    for (int k0 = 0; k0 < K; k0 += 16) {
        #pragma unroll
        for (int i = 0; i < 4; ++i) {
            int idx = tid + i * 256;
            int m  = idx >> 4;
            int kk = idx & 15;
            int gm = bm + m, gk = k0 + kk;
            As[kk][m] = (gm < M && gk < K) ? A[(size_t)gm*lda + gk] : 0.f;
            int gn = bn + m;
            Ws[kk][m] = (gn < N && gk < K) ? W[(size_t)gn*K + gk] : 0.f;
        }
        __syncthreads();
        #pragma unroll
        for (int kk = 0; kk < 16; ++kk) {
            float a[4], w[4];
            #pragma unroll
            for (int ii = 0; ii < 4; ++ii) a[ii] = As[kk][tm+ii];
            #pragma unroll
            for (int jj = 0; jj < 4; ++jj) w[jj] = Ws[kk][tn+jj];
            #pragma unroll
            for (int ii = 0; ii < 4; ++ii)
                #pragma unroll
                for (int jj = 0; jj < 4; ++jj)
                    acc[ii][jj] = fmaf(a[ii], w[jj], acc[ii][jj]);
        }
        __syncthreads();
    }
    #pragma unroll
    for (int ii = 0; ii < 4; ++ii) {
        int gm = bm + tm + ii;
        if (gm >= M) continue;
        #pragma unroll
        for (int jj = 0; jj < 4; ++jj) {
            int gn = bn + tn + jj;
            if (gn >= N) continue;
            float v = acc[ii][jj];
            if (bias) v += bias[gn];
            if (act == 1) v = (v > 20.f) ? v : log1pf(expf(v));
            size_t o = (size_t)gm*ldc + gn;
            if (accum) C[o] += v; else C[o] = v;
        }
    }
}

// ---------------- causal depthwise conv4 + bias + SiLU -> bf16 ----------------
__global__ __launch_bounds__(256) void conv_silu_kernel(
    const float* __restrict__ xz, const float* __restrict__ cw,
    const float* __restrict__ cb, __hip_bfloat16* __restrict__ u)
{
    int idx = blockIdx.x * 256 + threadIdx.x;
    if (idx >= BB*LL*DI) return;
    int d = idx % DI;
    int l = (idx / DI) % LL;
    int b = idx / (DI * LL);
    float acc = cb[d];
    #pragma unroll
    for (int k = 0; k < 4; ++k) {
        int ls = l - 3 + k;
        if (ls >= 0)
            acc = fmaf(xz[((size_t)(b*LL + ls))*(2*DI) + d], cw[d*4 + k], acc);
    }
    u[idx] = __float2bfloat16(acc / (1.f + __expf(-acc)));
}

// ================= chunk-parallel selective scan =================
__global__ __launch_bounds__(256) void scan_phaseA(
    const float* __restrict__ delta, const __hip_bfloat16* __restrict__ u,
    const float* __restrict__ dbl, const float* __restrict__ A_log,
    float* __restrict__ Psum, float* __restrict__ Hsum)
{
    const int d = blockIdx.x * 256 + threadIdx.x;
    const int c = blockIdx.y;
    const int b = blockIdx.z;
    float A[DS], P[DS], hl[DS];
    #pragma unroll
    for (int s = 0; s < DS; ++s) {
        A[s] = -expf(A_log[(size_t)d*DS + s]);
        P[s] = 1.f; hl[s] = 0.f;
    }
    const int t0 = c * CT;
    for (int t = t0; t < t0 + CT; ++t) {
        const size_t row = (size_t)b*LL + t;
        const float* bc = dbl + row*WXROWS + DTR;
        float dt = delta[row*DI + d];
        float du = dt * __bfloat162float(u[row*DI + d]);
        #pragma unroll
        for (int s = 0; s < DS; ++s) {
            float a = __expf(dt * A[s]);
            P[s] *= a;
            hl[s] = fmaf(a, hl[s], du * bc[s]);
        }
    }
    const size_t off = (((size_t)b*NC + c)*DI + d)*DS;
    #pragma unroll
    for (int s = 0; s < DS; ++s) { Psum[off+s] = P[s]; Hsum[off+s] = hl[s]; }
}

__global__ __launch_bounds__(256) void scan_phaseB(
    const float* __restrict__ Psum, const float* __restrict__ Hsum,
    float* __restrict__ Hin)
{
    const int gid = blockIdx.x * 256 + threadIdx.x;
    if (gid >= BB*DI*DS) return;
    const int b = gid / (DI*DS);
    const int r = gid % (DI*DS);
    float hc = 0.f;
    for (int c = 0; c < NC; ++c) {
        const size_t off = ((size_t)(b*NC + c))*DI*DS + r;
        Hin[off] = hc;
        hc = fmaf(Psum[off], hc, Hsum[off]);
    }
}

// Phase C: rerun recurrence from Hin, gated output -> bf16
__global__ __launch_bounds__(256) void scan_phaseC(
    const float* __restrict__ delta, const __hip_bfloat16* __restrict__ u,
    const float* __restrict__ dbl, const float* __restrict__ xz,
    const float* __restrict__ A_log, const float* __restrict__ Dsk,
    const float* __restrict__ Hin, __hip_bfloat16* __restrict__ yfull)
{
    const int d = blockIdx.x * 256 + threadIdx.x;
    const int c = blockIdx.y;
    const int b = blockIdx.z;
    float A[DS], h[DS];
    const size_t hoff = (((size_t)b*NC + c)*DI + d)*DS;
    #pragma unroll
    for (int s = 0; s < DS; ++s) {
        A[s] = -expf(A_log[(size_t)d*DS + s]);
        h[s] = Hin[hoff + s];
    }
    const float dsk = Dsk[d];
    const int t0 = c * CT;
    for (int t = t0; t < t0 + CT; ++t) {
        const size_t row = (size_t)b*LL + t;
        const float* bc = dbl + row*WXROWS + DTR;
        float dt = delta[row*DI + d];
        float ut = __bfloat162float(u[row*DI + d]);
        float du = dt * ut;
        float y = 0.f;
        #pragma unroll
        for (int s = 0; s < DS; ++s) {
            float a = __expf(dt * A[s]);
            h[s] = fmaf(a, h[s], du * bc[s]);
            y = fmaf(h[s], bc[DS+s], y);
        }
        float zt = xz[row*(2*DI) + DI + d];
        float sz = zt / (1.f + __expf(-zt));
        yfull[row*DI + d] = __float2bfloat16((y + ut * dsk) * sz);
    }
}

// ---------------- final rmsnorm + gather last valid token ----------------
__global__ __launch_bounds__(256) void final_kernel(
    const float* __restrict__ h, const float* __restrict__ w,
    const int* __restrict__ lengths, float* __restrict__ out)
{
    int b = blockIdx.x;
    int idx = lengths[b] - 1;
    const float* xr = h + ((size_t)b*LL + idx)*DM;
    float ss = 0.f;
    for (int j = threadIdx.x; j < DM; j += 256) { float v = xr[j]; ss += v*v; }
    #pragma unroll
    for (int off = 32; off > 0; off >>= 1) ss += __shfl_down(ss, off);
    __shared__ float red[4];
    int lane = threadIdx.x & 63, wv = threadIdx.x >> 6;
    if (lane == 0) red[wv] = ss;
    __syncthreads();
    if (threadIdx.x == 0) {
        float t = red[0] + red[1] + red[2] + red[3];
        red[0] = rsqrtf(t / (float)DM + 1e-5f);
    }
    __syncthreads();
    float r = red[0];
    for (int j = threadIdx.x; j < DM; j += 256)
        out[(size_t)b*DM + j] = xr[j] * w[j] * r;
}

extern "C" void kernel_launch(void* const* d_in, const int* in_sizes, int n_in,
                              void* d_out, int out_size, void* d_ws, size_t ws_size,
                              hipStream_t stream)
{
    const float* batch   = (const float*)d_in[0];
    const void*  mask    = d_in[1];
    const float* norm_w  = (const float*)d_in[2];
    const float* W_in    = (const float*)d_in[3];
    const float* conv_w  = (const float*)d_in[4];
    const float* conv_b  = (const float*)d_in[5];
    const float* W_x     = (const float*)d_in[6];
    const float* W_dt    = (const float*)d_in[7];
    const float* b_dt    = (const float*)d_in[8];
    const float* A_log   = (const float*)d_in[9];
    const float* D_skip  = (const float*)d_in[10];
    const float* W_out   = (const float*)d_in[11];
    const float* normf_w = (const float*)d_in[12];
    float* out = (float*)d_out;

    // workspace layout
    float* ws    = (float*)d_ws;
    float* h     = ws;                         // 1,572,864 f32
    float* xz    = h    + (size_t)NTOK*DM;     // 6,291,456 f32
    float* dbl   = xz   + (size_t)NTOK*2*DI;   //   163,840 f32
    float* delta = dbl  + (size_t)NTOK*WXROWS; // 3,145,728 f32
    float* Psum  = delta + (size_t)NTOK*DI;    // 1,572,864 f32 (also dblp partials)
    float* Hsum  = Psum + (size_t)BB*NC*DI*DS; // 1,572,864 f32
    float* Hin   = Hsum + (size_t)BB*NC*DI*DS; // 1,572,864 f32
    __hip_bfloat16* xn_bf  = (__hip_bfloat16*)(Hin + (size_t)BB*NC*DI*DS);
    __hip_bfloat16* y_bf   = xn_bf + (size_t)NTOK*DM;      // NTOK*DI
    __hip_bfloat16* u_bf   = y_bf + (size_t)NTOK*DI;       // NTOK*DI
    __hip_bfloat16* Win_bf = u_bf + (size_t)NTOK*DI;       // 2*DI*DM
    __hip_bfloat16* Wout_bf= Win_bf + (size_t)2*DI*DM;     // DM*DI
    __hip_bfloat16* Wxp_bf = Wout_bf + (size_t)DM*DI;      // 128*DI
    int*   lengths = (int*)(Wxp_bf + (size_t)128*DI);
    float* dblp = Psum;   // [SKS][NTOK][80] partials, dead before scanA writes Psum

    transpose_in_kernel<<<(BB*LL*DM + 255)/256, 256, 0, stream>>>(batch, h);
    lengths_kernel<<<1, 64, 0, stream>>>(mask, lengths);

    for (int i = 0; i < NL; ++i) {
        const float* Wi   = W_in  + (size_t)i * 2*DI * DM;
        const float* cwi  = conv_w + (size_t)i * DI * DC;
        const float* cbi  = conv_b + (size_t)i * DI;
        const float* Wxi  = W_x   + (size_t)i * WXROWS * DI;
        const float* Wdti = W_dt  + (size_t)i * DI * DTR;
        const float* bdti = b_dt  + (size_t)i * DI;
        const float* Ali  = A_log + (size_t)i * DI * DS;
        const float* Dski = D_skip + (size_t)i * DI;
        const float* Woi  = W_out + (size_t)i * DM * DI;

        // weight slices -> bf16
        cvt_bf16_kernel<<<(2*DI*DM/4 + 255)/256, 256, 0, stream>>>(Wi, Win_bf, 2*DI*DM);
        cvt_bf16_kernel<<<(DM*DI/4 + 255)/256, 256, 0, stream>>>(Woi, Wout_bf, DM*DI);
        cvt_pad_bf16_kernel<<<(128*DI/4 + 255)/256, 256, 0, stream>>>(
            Wxi, Wxp_bf, WXROWS*DI, 128*DI);

        // 1) pre-norm -> bf16
        rmsnorm_kernel<<<NTOK, 256, 0, stream>>>(h, norm_w + (size_t)i*DM, xn_bf);
        // 2) xz = xn @ W_in^T  (MFMA)  [2048 x 3072], K=768
        gemm_mfma_kernel<0><<<dim3(2*DI/128, NTOK/128), 256, 0, stream>>>(
            xn_bf, Win_bf, xz, NTOK, 2*DI, DM);
        // 3) causal conv + SiLU -> u_bf
        conv_silu_kernel<<<(BB*LL*DI + 255)/256, 256, 0, stream>>>(xz, cwi, cbi, u_bf);
        // 4) dbl = u @ W_x^T  [2048 x 80] (MFMA split-K + reduce)
        gemm_mfma_skinny<<<dim3(SKS, NTOK/128), 256, 0, stream>>>(u_bf, Wxp_bf, dblp);
        reduce_dbl_kernel<<<NTOK*WXROWS/256, 256, 0, stream>>>(dblp, dbl);
        // 5) delta = softplus(dtp @ W_dt^T + b_dt)  [2048 x 1536] (f32)
        gemm_bt_kernel<<<dim3((DI+63)/64, (NTOK+63)/64), 256, 0, stream>>>(
            dbl, WXROWS, Wdti, bdti, delta, DI, NTOK, DI, DTR, 1, 0);

        // chunk-parallel scan
        scan_phaseA<<<dim3(DI/256, NC, BB), 256, 0, stream>>>(
            delta, u_bf, dbl, Ali, Psum, Hsum);
        scan_phaseB<<<(BB*DI*DS + 255)/256, 256, 0, stream>>>(Psum, Hsum, Hin);
        scan_phaseC<<<dim3(DI/256, NC, BB), 256, 0, stream>>>(
            delta, u_bf, dbl, xz, Ali, Dski, Hin, y_bf);

        // 7) h += y @ W_out^T  (MFMA)  [2048 x 768], K=1536
        gemm_mfma_kernel<1><<<dim3(DM/128, NTOK/128), 256, 0, stream>>>(
            y_bf, Wout_bf, h, NTOK, DM, DI);
    }

    final_kernel<<<BB, 256, 0, stream>>>(h, normf_w, lengths, out);
}